// Round 11
// baseline (119.175 us; speedup 1.0000x reference)
//
#include <hip/hip_runtime.h>
#include <hip/hip_bf16.h>

#define BATCH 2
#define SEQ 2048
#define DMODEL 1024
#define NHEAD 16
#define DHEAD 64
#define NQKV 3072
#define DINNER 1024

typedef __attribute__((ext_vector_type(4))) short short4v;
typedef __attribute__((ext_vector_type(8))) short short8v;
typedef __attribute__((ext_vector_type(4))) float f32x4;

__device__ __forceinline__ unsigned short f2bf(float f) {
  union { float f; unsigned int u; } c; c.f = f;
  unsigned int u = c.u;
  u += 0x7fffu + ((u >> 16) & 1u);
  return (unsigned short)(u >> 16);
}

__device__ __forceinline__ float exp2_hw(float x) {  // v_exp_f32: D = 2^S0
  float r;
  asm("v_exp_f32 %0, %1" : "=v"(r) : "v"(x));
  return r;
}

__device__ __forceinline__ short8v load_frag(const unsigned short* p0, const unsigned short* p1) {
  union { short8v v8; short4v v4[2]; } u;
  u.v4[0] = *(const short4v*)p0;
  u.v4[1] = *(const short4v*)p1;
  return u.v8;
}

#define GL16(gp, lp)                                             \
  __builtin_amdgcn_global_load_lds(                              \
      (__attribute__((address_space(1))) void*)(gp),             \
      (__attribute__((address_space(3))) void*)(lp), 16, 0, 0)

// ---------------- transpose + cast fp32 [K][N] -> bf16 [N][K] ----------------
__global__ __launch_bounds__(256) void transpose_cast_kernel(const float* __restrict__ in,
                                                             unsigned short* __restrict__ out,
                                                             int K, int N) {
  __shared__ float tile[32][33];
  const int tiles_n = N >> 5;
  const int tn = blockIdx.x % tiles_n;
  const int tk = blockIdx.x / tiles_n;
  const int k0 = tk << 5, n0 = tn << 5;
  const int t = threadIdx.x;
#pragma unroll
  for (int p = 0; p < 4; p++) {
    const int e = p * 256 + t;
    const int r = e >> 5, c = e & 31;
    tile[r][c] = in[(size_t)(k0 + r) * N + n0 + c];
  }
  __syncthreads();
#pragma unroll
  for (int p = 0; p < 4; p++) {
    const int e = p * 256 + t;
    const int r = e >> 5, c = e & 31;
    out[(size_t)(n0 + r) * K + k0 + c] = f2bf(tile[c][r]);
  }
}

// ---------------- RMSNorm (F.normalize * sqrt(dim) * gamma) -> bf16 ----------
__global__ __launch_bounds__(256) void rmsnorm_kernel(const float* __restrict__ x,
                                                      const float* __restrict__ gamma,
                                                      unsigned short* __restrict__ out) {
  const int row = blockIdx.x;
  const int t = threadIdx.x;
  const float* xr = x + (size_t)row * DMODEL;
  float4 v = ((const float4*)xr)[t];
  float ss = v.x * v.x + v.y * v.y + v.z * v.z + v.w * v.w;
#pragma unroll
  for (int off = 1; off < 64; off <<= 1) ss += __shfl_xor(ss, off);
  __shared__ float wss[4];
  if ((t & 63) == 0) wss[t >> 6] = ss;
  __syncthreads();
  const float tot = wss[0] + wss[1] + wss[2] + wss[3];
  float l2 = sqrtf(tot);
  l2 = fmaxf(l2, 1e-12f);
  const float s = 32.0f / l2;  // sqrt(1024)/l2
  const float4 gm = ((const float4*)gamma)[t];
  unsigned short o[4];
  o[0] = f2bf(v.x * s * gm.x);
  o[1] = f2bf(v.y * s * gm.y);
  o[2] = f2bf(v.z * s * gm.z);
  o[3] = f2bf(v.w * s * gm.w);
  unsigned short* op = out + (size_t)row * DMODEL + t * 4;
  *(short4v*)op = *(short4v*)o;
}

// ---------------- shared GEMM core: double-buffered global_load_lds staging --
#define BM 128
#define BN 128
#define BKT 32
#define TILE_E (BM * BKT)

__device__ void gemm_core(const unsigned short* __restrict__ A,
                          const unsigned short* __restrict__ Bt, int K, int rowBase,
                          int colBase, unsigned short* sA, unsigned short* sB,
                          f32x4 acc[4][4]) {
  const int t = threadIdx.x;
  const int lane = t & 63, wave = t >> 6;
  const int l15 = lane & 15, g = lane >> 4;
  const int wr = (wave >> 1) * 64, wc = (wave & 1) * 64;
#pragma unroll
  for (int m = 0; m < 4; m++)
#pragma unroll
    for (int n = 0; n < 4; n++) acc[m][n] = (f32x4){0.f, 0.f, 0.f, 0.f};
  const int r0 = t >> 2, o0 = (t & 3) * 8;
  const unsigned short* Ag0 = A + (size_t)(rowBase + r0) * K + o0;
  const unsigned short* Ag1 = A + (size_t)(rowBase + r0 + 64) * K + o0;
  const unsigned short* Bg0 = Bt + (size_t)(colBase + r0) * K + o0;
  const unsigned short* Bg1 = Bt + (size_t)(colBase + r0 + 64) * K + o0;
  // prologue: tile 0 -> half 0
  GL16(Ag0, sA + t * 8);
  GL16(Ag1, sA + (t + 256) * 8);
  GL16(Bg0, sB + t * 8);
  GL16(Bg1, sB + (t + 256) * 8);
  __syncthreads();  // drains vmcnt -> tile 0 resident
  int cur = 0;
  for (int k0 = 0; k0 < K; k0 += BKT, cur ^= 1) {
    if (k0 + BKT < K) {  // prefetch next tile into the other half
      const int nxto = (cur ^ 1) * TILE_E;
      GL16(Ag0 + k0 + BKT, sA + nxto + t * 8);
      GL16(Ag1 + k0 + BKT, sA + nxto + (t + 256) * 8);
      GL16(Bg0 + k0 + BKT, sB + nxto + t * 8);
      GL16(Bg1 + k0 + BKT, sB + nxto + (t + 256) * 8);
    }
    const unsigned short* sAc = sA + cur * TILE_E;
    const unsigned short* sBc = sB + cur * TILE_E;
    short8v af[4], bf[4];
#pragma unroll
    for (int m = 0; m < 4; m++)
      af[m] = *(const short8v*)(sAc + (wr + m * 16 + l15) * BKT + 8 * g);
#pragma unroll
    for (int n = 0; n < 4; n++)
      bf[n] = *(const short8v*)(sBc + (wc + n * 16 + l15) * BKT + 8 * g);
#pragma unroll
    for (int m = 0; m < 4; m++)
#pragma unroll
      for (int n = 0; n < 4; n++)
        acc[m][n] = __builtin_amdgcn_mfma_f32_16x16x32_bf16(af[m], bf[n], acc[m][n], 0, 0, 0);
    __syncthreads();  // waves done with cur + prefetch complete
  }
}

// ---------------- QKV GEMM + scatter epilogue (V stored transposed) ----------
// q pre-scaled by d^-0.5 * log2(e) so attention softmax runs in exp2 domain.
__global__ __launch_bounds__(256) void qkv_gemm_kernel(const unsigned short* __restrict__ A,
                                                       const unsigned short* __restrict__ Bt,
                                                       unsigned short* __restrict__ qb,
                                                       unsigned short* __restrict__ kb,
                                                       unsigned short* __restrict__ vtb) {
  __shared__ __align__(16) unsigned short sA[2 * TILE_E];
  __shared__ __align__(16) unsigned short sB[2 * TILE_E];
  const int nbn = NQKV / BN;  // 24
  const int bm = blockIdx.x / nbn, bn = blockIdx.x % nbn;
  f32x4 acc[4][4];
  gemm_core(A, Bt, DMODEL, bm * BM, bn * BN, sA, sB, acc);
  const int t = threadIdx.x, lane = t & 63, wave = t >> 6;
  const int l15 = lane & 15, g = lane >> 4;
  const int wr = (wave >> 1) * 64, wc = (wave & 1) * 64;
#pragma unroll
  for (int m = 0; m < 4; m++)
#pragma unroll
    for (int n = 0; n < 4; n++) {
      const int col = bn * BN + wc + n * 16 + l15;
      const int part = col >> 10;
      const int h = (col >> 6) & 15;
      const int d = col & 63;
      const int row0 = bm * BM + wr + m * 16 + 4 * g;
      const int bb = row0 >> 11, i0 = row0 & 2047;
      if (part == 2) {
        // V^T layout: [b*16+h][d][n] -- 4 consecutive i values vectorize
        union { short4v v; unsigned short u[4]; } pk;
#pragma unroll
        for (int r = 0; r < 4; r++) pk.u[r] = f2bf(acc[m][n][r]);
        *(short4v*)(vtb + ((size_t)(bb * NHEAD + h) * DHEAD + d) * SEQ + i0) = pk.v;
      } else {
#pragma unroll
        for (int r = 0; r < 4; r++) {
          const size_t idx = (((size_t)(bb * NHEAD + h)) * SEQ + i0 + r) * DHEAD + d;
          const float v = acc[m][n][r];
          if (part == 0) qb[idx] = f2bf(v * 0.18033688f);  // 0.125 * log2(e)
          else kb[idx] = f2bf(v);
        }
      }
    }
}

// ---------------- output GEMM: d_out = attn_out @ w_out ----------------------
__global__ __launch_bounds__(256) void out_gemm_kernel(const unsigned short* __restrict__ A,
                                                       const unsigned short* __restrict__ Bt,
                                                       float* __restrict__ C) {
  __shared__ __align__(16) unsigned short sA[2 * TILE_E];
  __shared__ __align__(16) unsigned short sB[2 * TILE_E];
  const int nbn = DMODEL / BN;  // 8
  const int bm = blockIdx.x / nbn, bn = blockIdx.x % nbn;
  f32x4 acc[4][4];
  gemm_core(A, Bt, DINNER, bm * BM, bn * BN, sA, sB, acc);
  const int t = threadIdx.x, lane = t & 63, wave = t >> 6;
  const int l15 = lane & 15, g = lane >> 4;
  const int wr = (wave >> 1) * 64, wc = (wave & 1) * 64;
#pragma unroll
  for (int m = 0; m < 4; m++)
#pragma unroll
    for (int n = 0; n < 4; n++) {
      const int col = bn * BN + wc + n * 16 + l15;
#pragma unroll
      for (int r = 0; r < 4; r++) {
        const int row = bm * BM + wr + m * 16 + 4 * g + r;
        C[(size_t)row * DMODEL + col] = acc[m][n][r];
      }
    }
}

// ---------------- causal flash attention: 128-row blocks, 8 waves ------------
// Block = 128 q-rows (8 waves x 16). K/V staged once per block per 64-key
// step (one 16B chunk per thread): half the staging issue + L2 traffic of
// 64-row blocks at the SAME residency (2 blocks/CU x 8 waves = 4 waves/SIMD).
// K via global_load_lds + both-sides XOR swizzle; V^T reg-staged into padded
// [64][72]. Swapped QK/PV keep softmax lane-local (q = l15). Denominator is
// accumulated by MFMA with an all-ones A fragment (2 MFMA/step replace 32
// VALU adds + the final cross-lane reduce). Softmax in exp2 domain (q was
// pre-scaled by log2e/8; v_exp_f32 IS 2^x). Defer-max: rescale only on growth.
__global__ __launch_bounds__(512, 4) void attn_kernel(const unsigned short* __restrict__ qb,
                                                      const unsigned short* __restrict__ kb,
                                                      const unsigned short* __restrict__ vtb,
                                                      unsigned short* __restrict__ ob) {
  __shared__ __align__(16) unsigned short sK[2][64 * 64];  // 8KB each, swizzled
  __shared__ __align__(16) unsigned short sV[2][64 * 72];  // padded rows (144B)
  const int t = threadIdx.x, lane = t & 63, wave = t >> 6;  // wave 0..7
  const int l15 = lane & 15, g = lane >> 4;
  const int bh = blockIdx.x & 31;        // low bits -> same-bh blocks same XCD
  const int qord = blockIdx.x >> 5;      // 0..15
  // constant-sum map: co-resident pair {qord, qord+8} -> steps sum = 36
  const int qblk = (qord < 8) ? 15 - qord : qord - 8;
  const int qrow = qblk * 128 + wave * 16 + l15;
  const unsigned short* qptr = qb + (size_t)bh * SEQ * DHEAD;
  const unsigned short* kptr = kb + (size_t)bh * SEQ * DHEAD;
  const unsigned short* vtptr = vtb + (size_t)bh * DHEAD * SEQ;

  // staging geometry: 512 threads x one 16B chunk for K and for V
  const int kr = t >> 3, kj = ((t & 7) ^ (kr & 7)) * 8;  // swizzled global src
  const int vr = t >> 3, vo = (t & 7) * 8;

  // Q fragments (B operand): l15 = q, elems = d (contiguous 8)
  short8v qf[2];
#pragma unroll
  for (int kk = 0; kk < 2; kk++)
    qf[kk] = *(const short8v*)(qptr + (size_t)qrow * DHEAD + kk * 32 + 8 * g);

  // all-ones bf16 fragment for the denominator MFMA
  union { short8v v; unsigned short u[8]; } ones;
#pragma unroll
  for (int j = 0; j < 8; j++) ones.u[j] = 0x3F80;

  float rm = -__builtin_inff();
  f32x4 acc_l = (f32x4){0.f, 0.f, 0.f, 0.f};  // denominator (all rows equal)
  f32x4 acc_o[4];  // [df]: col = q = l15, row(4g+r) = d = df*16+4g+r
#pragma unroll
  for (int df = 0; df < 4; df++) acc_o[df] = (f32x4){0.f, 0.f, 0.f, 0.f};

  const int nsteps = 2 * qblk + 2;                 // 64-key steps staged
  const int smax_w = 2 * qblk + (wave >> 2);       // last step this wave needs

  // prologue: stage step 0 into buf 0
  GL16(kptr + (size_t)kr * DHEAD + kj, sK[0] + t * 8);
  {
    short8v va = *(const short8v*)(vtptr + (size_t)vr * SEQ + vo);
    *(short8v*)(sV[0] + vr * 72 + vo) = va;
  }
  __syncthreads();

  int cur = 0;
  for (int s = 0; s < nsteps; ++s, cur ^= 1) {
    const int nxt = cur ^ 1;
    const bool more = (s + 1 < nsteps);
    short8v va;
    if (more) {  // issue next step's loads before compute (latency hides)
      const int k0n = (s + 1) * 64;
      GL16(kptr + (size_t)(k0n + kr) * DHEAD + kj, sK[nxt] + t * 8);
      va = *(const short8v*)(vtptr + (size_t)vr * SEQ + k0n + vo);
    }
    if (s <= smax_w) {
      const int k0 = s * 64;
      const unsigned short* sKc = sK[cur];
      const unsigned short* sVc = sV[cur];
      // K frags: n4 = key group (0..3); row = n4*16+l15 (swizzled read)
      short8v kf[4][2];
#pragma unroll
      for (int n4 = 0; n4 < 4; n4++) {
        const int row = n4 * 16 + l15;
#pragma unroll
        for (int kk = 0; kk < 2; kk++)
          kf[n4][kk] = *(const short8v*)(sKc + row * 64 + (((kk * 4 + g) ^ (row & 7)) * 8));
      }
      // QK^T swapped: s4[n4] = D[key][q], key = k0+n4*16+4g+r, q = qrow (l15)
      f32x4 s4[4];
#pragma unroll
      for (int n4 = 0; n4 < 4; n4++) s4[n4] = (f32x4){0.f, 0.f, 0.f, 0.f};
#pragma unroll
      for (int n4 = 0; n4 < 4; n4++)
#pragma unroll
        for (int kk = 0; kk < 2; kk++)
          s4[n4] = __builtin_amdgcn_mfma_f32_16x16x32_bf16(kf[n4][kk], qf[kk],
                                                           s4[n4], 0, 0, 0);
      if (s == smax_w) {  // diagonal step: causal mask
#pragma unroll
        for (int n4 = 0; n4 < 4; n4++)
#pragma unroll
          for (int r = 0; r < 4; r++)
            if (k0 + n4 * 16 + 4 * g + r > qrow) s4[n4][r] = -__builtin_inff();
      }
      float mx = s4[0][0];
#pragma unroll
      for (int n4 = 0; n4 < 4; n4++)
#pragma unroll
        for (int r = 0; r < 4; r++)
          if (n4 || r) mx = fmaxf(mx, s4[n4][r]);
      if (!__all(mx <= rm)) {  // row max grew: reduce + rescale (rare)
        mx = fmaxf(mx, __shfl_xor(mx, 16));
        mx = fmaxf(mx, __shfl_xor(mx, 32));
        const float nm = fmaxf(rm, mx);
        const float al = exp2_hw(rm - nm);
        rm = nm;
#pragma unroll
        for (int r = 0; r < 4; r++) acc_l[r] *= al;
#pragma unroll
        for (int df = 0; df < 4; df++)
#pragma unroll
          for (int r = 0; r < 4; r++) acc_o[df][r] *= al;
      }
#pragma unroll
      for (int n4 = 0; n4 < 4; n4++)
#pragma unroll
        for (int r = 0; r < 4; r++) s4[n4][r] = exp2_hw(s4[n4][r] - rm);
      unsigned int pw[8];
#pragma unroll
      for (int n4 = 0; n4 < 4; n4++) {
        asm("v_cvt_pk_bf16_f32 %0, %1, %2"
            : "=v"(pw[n4 * 2]) : "v"(s4[n4][0]), "v"(s4[n4][1]));
        asm("v_cvt_pk_bf16_f32 %0, %1, %2"
            : "=v"(pw[n4 * 2 + 1]) : "v"(s4[n4][2]), "v"(s4[n4][3]));
      }
      union { short8v v; unsigned int wd[4]; } paA, paB;
      paA.wd[0] = pw[0]; paA.wd[1] = pw[1]; paA.wd[2] = pw[2]; paA.wd[3] = pw[3];
      paB.wd[0] = pw[4]; paB.wd[1] = pw[5]; paB.wd[2] = pw[6]; paB.wd[3] = pw[7];
      // denominator: all-ones A fragment -> every D row = sum_k P[k][q]
      acc_l = __builtin_amdgcn_mfma_f32_16x16x32_bf16(ones.v, paA.v, acc_l, 0, 0, 0);
      acc_l = __builtin_amdgcn_mfma_f32_16x16x32_bf16(ones.v, paB.v, acc_l, 0, 0, 0);
      // V frags + PV
#pragma unroll
      for (int df = 0; df < 4; df++) {
        const unsigned short* pv0 = sVc + (df * 16 + l15) * 72 + 4 * g;
        const short8v vfa = load_frag(pv0, pv0 + 16);
        acc_o[df] = __builtin_amdgcn_mfma_f32_16x16x32_bf16(vfa, paA.v, acc_o[df], 0, 0, 0);
        const unsigned short* pv1 = pv0 + 32;
        const short8v vfb = load_frag(pv1, pv1 + 16);
        acc_o[df] = __builtin_amdgcn_mfma_f32_16x16x32_bf16(vfb, paB.v, acc_o[df], 0, 0, 0);
      }
    }
    if (more) *(short8v*)(sV[nxt] + vr * 72 + vo) = va;
    __syncthreads();
  }

  // epilogue: denominator already complete per-lane (MFMA reduced over keys)
  const int bb = bh >> 4, hh = bh & 15;
  const float inv = 1.0f / acc_l[0];
#pragma unroll
  for (int df = 0; df < 4; df++) {
    union { short4v v; unsigned short u[4]; } pk4;
#pragma unroll
    for (int r = 0; r < 4; r++) pk4.u[r] = f2bf(acc_o[df][r] * inv);
    *(short4v*)(ob + ((size_t)bb * SEQ + qrow) * DINNER + hh * DHEAD + df * 16 + 4 * g) =
        pk4.v;
  }
}

extern "C" void kernel_launch(void* const* d_in, const int* in_sizes, int n_in,
                              void* d_out, int out_size, void* d_ws, size_t ws_size,
                              hipStream_t stream) {
  (void)in_sizes; (void)n_in; (void)out_size; (void)ws_size;
  const float* x = (const float*)d_in[0];
  const float* gamma = (const float*)d_in[1];
  const float* w_qkv = (const float*)d_in[2];
  const float* w_out = (const float*)d_in[3];
  float* out = (float*)d_out;
  char* ws = (char*)d_ws;
  unsigned short* wqkvT = (unsigned short*)(ws);                // 6291456 B
  unsigned short* woutT = (unsigned short*)(ws + 6291456);      // 2097152 B
  unsigned short* normed = (unsigned short*)(ws + 8388608);     // 8388608 B
  unsigned short* qbuf = (unsigned short*)(ws + 16777216);      // 8388608 B
  unsigned short* kbuf = (unsigned short*)(ws + 25165824);      // 8388608 B
  unsigned short* vtbuf = (unsigned short*)(ws + 33554432);     // 8388608 B (transposed V)
  unsigned short* aout = (unsigned short*)(ws + 41943040);      // 8388608 B

  hipLaunchKernelGGL(transpose_cast_kernel, dim3((DMODEL / 32) * (NQKV / 32)), dim3(256), 0,
                     stream, w_qkv, wqkvT, DMODEL, NQKV);
  hipLaunchKernelGGL(transpose_cast_kernel, dim3((DINNER / 32) * (DMODEL / 32)), dim3(256), 0,
                     stream, w_out, woutT, DINNER, DMODEL);
  hipLaunchKernelGGL(rmsnorm_kernel, dim3(BATCH * SEQ), dim3(256), 0, stream, x, gamma, normed);
  hipLaunchKernelGGL(qkv_gemm_kernel, dim3((BATCH * SEQ / BM) * (NQKV / BN)), dim3(256), 0,
                     stream, normed, wqkvT, qbuf, kbuf, vtbuf);
  hipLaunchKernelGGL(attn_kernel, dim3(BATCH * NHEAD * 16), dim3(512), 0, stream,
                     qbuf, kbuf, vtbuf, aout);
  hipLaunchKernelGGL(out_gemm_kernel, dim3((BATCH * SEQ / BM) * (DMODEL / BN)), dim3(256), 0,
                     stream, aout, woutT, out);
}

// Round 12
// 116.130 us; speedup vs baseline: 1.0262x; 1.0262x over previous
//
#include <hip/hip_runtime.h>
#include <hip/hip_bf16.h>

#define BATCH 2
#define SEQ 2048
#define DMODEL 1024
#define NHEAD 16
#define DHEAD 64
#define NQKV 3072
#define DINNER 1024

typedef __attribute__((ext_vector_type(4))) short short4v;
typedef __attribute__((ext_vector_type(8))) short short8v;
typedef __attribute__((ext_vector_type(4))) float f32x4;

__device__ __forceinline__ unsigned short f2bf(float f) {
  union { float f; unsigned int u; } c; c.f = f;
  unsigned int u = c.u;
  u += 0x7fffu + ((u >> 16) & 1u);
  return (unsigned short)(u >> 16);
}

__device__ __forceinline__ float exp2_hw(float x) {  // v_exp_f32: D = 2^S0
  float r;
  asm("v_exp_f32 %0, %1" : "=v"(r) : "v"(x));
  return r;
}

__device__ __forceinline__ short8v load_frag(const unsigned short* p0, const unsigned short* p1) {
  union { short8v v8; short4v v4[2]; } u;
  u.v4[0] = *(const short4v*)p0;
  u.v4[1] = *(const short4v*)p1;
  return u.v8;
}

#define GL16(gp, lp)                                             \
  __builtin_amdgcn_global_load_lds(                              \
      (__attribute__((address_space(1))) void*)(gp),             \
      (__attribute__((address_space(3))) void*)(lp), 16, 0, 0)

// ---------------- transpose + cast fp32 [K][N] -> bf16 [N][K] ----------------
__global__ __launch_bounds__(256) void transpose_cast_kernel(const float* __restrict__ in,
                                                             unsigned short* __restrict__ out,
                                                             int K, int N) {
  __shared__ float tile[32][33];
  const int tiles_n = N >> 5;
  const int tn = blockIdx.x % tiles_n;
  const int tk = blockIdx.x / tiles_n;
  const int k0 = tk << 5, n0 = tn << 5;
  const int t = threadIdx.x;
#pragma unroll
  for (int p = 0; p < 4; p++) {
    const int e = p * 256 + t;
    const int r = e >> 5, c = e & 31;
    tile[r][c] = in[(size_t)(k0 + r) * N + n0 + c];
  }
  __syncthreads();
#pragma unroll
  for (int p = 0; p < 4; p++) {
    const int e = p * 256 + t;
    const int r = e >> 5, c = e & 31;
    out[(size_t)(n0 + r) * K + k0 + c] = f2bf(tile[c][r]);
  }
}

// ---------------- RMSNorm (F.normalize * sqrt(dim) * gamma) -> bf16 ----------
__global__ __launch_bounds__(256) void rmsnorm_kernel(const float* __restrict__ x,
                                                      const float* __restrict__ gamma,
                                                      unsigned short* __restrict__ out) {
  const int row = blockIdx.x;
  const int t = threadIdx.x;
  const float* xr = x + (size_t)row * DMODEL;
  float4 v = ((const float4*)xr)[t];
  float ss = v.x * v.x + v.y * v.y + v.z * v.z + v.w * v.w;
#pragma unroll
  for (int off = 1; off < 64; off <<= 1) ss += __shfl_xor(ss, off);
  __shared__ float wss[4];
  if ((t & 63) == 0) wss[t >> 6] = ss;
  __syncthreads();
  const float tot = wss[0] + wss[1] + wss[2] + wss[3];
  float l2 = sqrtf(tot);
  l2 = fmaxf(l2, 1e-12f);
  const float s = 32.0f / l2;  // sqrt(1024)/l2
  const float4 gm = ((const float4*)gamma)[t];
  unsigned short o[4];
  o[0] = f2bf(v.x * s * gm.x);
  o[1] = f2bf(v.y * s * gm.y);
  o[2] = f2bf(v.z * s * gm.z);
  o[3] = f2bf(v.w * s * gm.w);
  unsigned short* op = out + (size_t)row * DMODEL + t * 4;
  *(short4v*)op = *(short4v*)o;
}

// ---------------- shared GEMM core: double-buffered global_load_lds staging --
#define BM 128
#define BN 128
#define BKT 32
#define TILE_E (BM * BKT)

__device__ void gemm_core(const unsigned short* __restrict__ A,
                          const unsigned short* __restrict__ Bt, int K, int rowBase,
                          int colBase, unsigned short* sA, unsigned short* sB,
                          f32x4 acc[4][4]) {
  const int t = threadIdx.x;
  const int lane = t & 63, wave = t >> 6;
  const int l15 = lane & 15, g = lane >> 4;
  const int wr = (wave >> 1) * 64, wc = (wave & 1) * 64;
#pragma unroll
  for (int m = 0; m < 4; m++)
#pragma unroll
    for (int n = 0; n < 4; n++) acc[m][n] = (f32x4){0.f, 0.f, 0.f, 0.f};
  const int r0 = t >> 2, o0 = (t & 3) * 8;
  const unsigned short* Ag0 = A + (size_t)(rowBase + r0) * K + o0;
  const unsigned short* Ag1 = A + (size_t)(rowBase + r0 + 64) * K + o0;
  const unsigned short* Bg0 = Bt + (size_t)(colBase + r0) * K + o0;
  const unsigned short* Bg1 = Bt + (size_t)(colBase + r0 + 64) * K + o0;
  // prologue: tile 0 -> half 0
  GL16(Ag0, sA + t * 8);
  GL16(Ag1, sA + (t + 256) * 8);
  GL16(Bg0, sB + t * 8);
  GL16(Bg1, sB + (t + 256) * 8);
  __syncthreads();  // drains vmcnt -> tile 0 resident
  int cur = 0;
  for (int k0 = 0; k0 < K; k0 += BKT, cur ^= 1) {
    if (k0 + BKT < K) {  // prefetch next tile into the other half
      const int nxto = (cur ^ 1) * TILE_E;
      GL16(Ag0 + k0 + BKT, sA + nxto + t * 8);
      GL16(Ag1 + k0 + BKT, sA + nxto + (t + 256) * 8);
      GL16(Bg0 + k0 + BKT, sB + nxto + t * 8);
      GL16(Bg1 + k0 + BKT, sB + nxto + (t + 256) * 8);
    }
    const unsigned short* sAc = sA + cur * TILE_E;
    const unsigned short* sBc = sB + cur * TILE_E;
    short8v af[4], bf[4];
#pragma unroll
    for (int m = 0; m < 4; m++)
      af[m] = *(const short8v*)(sAc + (wr + m * 16 + l15) * BKT + 8 * g);
#pragma unroll
    for (int n = 0; n < 4; n++)
      bf[n] = *(const short8v*)(sBc + (wc + n * 16 + l15) * BKT + 8 * g);
#pragma unroll
    for (int m = 0; m < 4; m++)
#pragma unroll
      for (int n = 0; n < 4; n++)
        acc[m][n] = __builtin_amdgcn_mfma_f32_16x16x32_bf16(af[m], bf[n], acc[m][n], 0, 0, 0);
    __syncthreads();  // waves done with cur + prefetch complete
  }
}

// ---------------- QKV GEMM + scatter epilogue (V stored transposed) ----------
// q pre-scaled by d^-0.5 * log2(e) so attention softmax runs in exp2 domain.
__global__ __launch_bounds__(256) void qkv_gemm_kernel(const unsigned short* __restrict__ A,
                                                       const unsigned short* __restrict__ Bt,
                                                       unsigned short* __restrict__ qb,
                                                       unsigned short* __restrict__ kb,
                                                       unsigned short* __restrict__ vtb) {
  __shared__ __align__(16) unsigned short sA[2 * TILE_E];
  __shared__ __align__(16) unsigned short sB[2 * TILE_E];
  const int nbn = NQKV / BN;  // 24
  const int bm = blockIdx.x / nbn, bn = blockIdx.x % nbn;
  f32x4 acc[4][4];
  gemm_core(A, Bt, DMODEL, bm * BM, bn * BN, sA, sB, acc);
  const int t = threadIdx.x, lane = t & 63, wave = t >> 6;
  const int l15 = lane & 15, g = lane >> 4;
  const int wr = (wave >> 1) * 64, wc = (wave & 1) * 64;
#pragma unroll
  for (int m = 0; m < 4; m++)
#pragma unroll
    for (int n = 0; n < 4; n++) {
      const int col = bn * BN + wc + n * 16 + l15;
      const int part = col >> 10;
      const int h = (col >> 6) & 15;
      const int d = col & 63;
      const int row0 = bm * BM + wr + m * 16 + 4 * g;
      const int bb = row0 >> 11, i0 = row0 & 2047;
      if (part == 2) {
        // V^T layout: [b*16+h][d][n] -- 4 consecutive i values vectorize
        union { short4v v; unsigned short u[4]; } pk;
#pragma unroll
        for (int r = 0; r < 4; r++) pk.u[r] = f2bf(acc[m][n][r]);
        *(short4v*)(vtb + ((size_t)(bb * NHEAD + h) * DHEAD + d) * SEQ + i0) = pk.v;
      } else {
#pragma unroll
        for (int r = 0; r < 4; r++) {
          const size_t idx = (((size_t)(bb * NHEAD + h)) * SEQ + i0 + r) * DHEAD + d;
          const float v = acc[m][n][r];
          if (part == 0) qb[idx] = f2bf(v * 0.18033688f);  // 0.125 * log2(e)
          else kb[idx] = f2bf(v);
        }
      }
    }
}

// ---------------- output GEMM: d_out = attn_out @ w_out ----------------------
__global__ __launch_bounds__(256) void out_gemm_kernel(const unsigned short* __restrict__ A,
                                                       const unsigned short* __restrict__ Bt,
                                                       float* __restrict__ C) {
  __shared__ __align__(16) unsigned short sA[2 * TILE_E];
  __shared__ __align__(16) unsigned short sB[2 * TILE_E];
  const int nbn = DMODEL / BN;  // 8
  const int bm = blockIdx.x / nbn, bn = blockIdx.x % nbn;
  f32x4 acc[4][4];
  gemm_core(A, Bt, DINNER, bm * BM, bn * BN, sA, sB, acc);
  const int t = threadIdx.x, lane = t & 63, wave = t >> 6;
  const int l15 = lane & 15, g = lane >> 4;
  const int wr = (wave >> 1) * 64, wc = (wave & 1) * 64;
#pragma unroll
  for (int m = 0; m < 4; m++)
#pragma unroll
    for (int n = 0; n < 4; n++) {
      const int col = bn * BN + wc + n * 16 + l15;
#pragma unroll
      for (int r = 0; r < 4; r++) {
        const int row = bm * BM + wr + m * 16 + 4 * g + r;
        C[(size_t)row * DMODEL + col] = acc[m][n][r];
      }
    }
}

// ---------------- causal flash attention: 64-row blocks, 4 blocks/CU ---------
// R9 structure (verified 43.5us): block = 64 q-rows (4 waves x 16), grid 1024
// -> 4 INDEPENDENT blocks/CU overlap each other's barrier drains; constant-sum
// qblk map equalizes co-resident step totals. K via global_load_lds +
// both-sides XOR swizzle; V^T reg-staged into padded [64][72]. Swapped QK/PV
// keep softmax lane-local (q = l15). VALU cuts (verified correct in R11):
// exp2-domain softmax (q pre-scaled by log2e/8; v_exp_f32 IS 2^x) and MFMA
// ones-fragment denominator (2 MFMA/step replace 32 VALU adds + final reduce).
__global__ __launch_bounds__(256, 4) void attn_kernel(const unsigned short* __restrict__ qb,
                                                      const unsigned short* __restrict__ kb,
                                                      const unsigned short* __restrict__ vtb,
                                                      unsigned short* __restrict__ ob) {
  __shared__ __align__(16) unsigned short sK[2][64 * 64];  // 8KB each, swizzled
  __shared__ __align__(16) unsigned short sV[2][64 * 72];  // padded rows (144B)
  const int t = threadIdx.x, lane = t & 63, wave = t >> 6;
  const int l15 = lane & 15, g = lane >> 4;
  const int bh = blockIdx.x & 31;        // low bits -> same-bh blocks same XCD
  const int qord = blockIdx.x >> 5;      // 0..31
  // constant-sum map: co-resident quadruple {q, q+8, q+16, q+24} sums to 62
  const int qblk = (qord < 8) ? 31 - qord
                 : (qord < 16) ? qord - 8
                 : (qord < 24) ? 39 - qord
                 : qord - 16;
  const int qrow = qblk * 64 + wave * 16 + l15;
  const unsigned short* qptr = qb + (size_t)bh * SEQ * DHEAD;
  const unsigned short* kptr = kb + (size_t)bh * SEQ * DHEAD;
  const unsigned short* vtptr = vtb + (size_t)bh * DHEAD * SEQ;

  // staging geometry (256 threads, 2 x 16B chunks each for K and V)
  const int kr0 = t >> 3, kj0 = ((t & 7) ^ (kr0 & 7)) * 8;
  const int kr1 = (t + 256) >> 3, kj1 = ((t & 7) ^ (kr1 & 7)) * 8;
  const int vr0 = t >> 3, vo0 = (t & 7) * 8;
  const int vr1 = (t + 256) >> 3, vo1 = (t & 7) * 8;

  // Q fragments (B operand): l15 = q, elems = d (contiguous 8)
  short8v qf[2];
#pragma unroll
  for (int kk = 0; kk < 2; kk++)
    qf[kk] = *(const short8v*)(qptr + (size_t)qrow * DHEAD + kk * 32 + 8 * g);

  // all-ones bf16 fragment for the denominator MFMA
  union { short8v v; unsigned short u[8]; } ones;
#pragma unroll
  for (int j = 0; j < 8; j++) ones.u[j] = 0x3F80;

  float rm = -__builtin_inff();
  f32x4 acc_l = (f32x4){0.f, 0.f, 0.f, 0.f};  // denominator (rows identical)
  f32x4 acc_o[4];  // [df]: col = q = l15, row(4g+r) = d = df*16+4g+r
#pragma unroll
  for (int df = 0; df < 4; df++) acc_o[df] = (f32x4){0.f, 0.f, 0.f, 0.f};

  const int nsteps = qblk + 1;  // 64-key steps

  // prologue: stage step 0 into buf 0
  GL16(kptr + (size_t)kr0 * DHEAD + kj0, sK[0] + t * 8);
  GL16(kptr + (size_t)kr1 * DHEAD + kj1, sK[0] + (t + 256) * 8);
  {
    short8v va = *(const short8v*)(vtptr + (size_t)vr0 * SEQ + vo0);
    short8v vb = *(const short8v*)(vtptr + (size_t)vr1 * SEQ + vo1);
    *(short8v*)(sV[0] + vr0 * 72 + vo0) = va;
    *(short8v*)(sV[0] + vr1 * 72 + vo1) = vb;
  }
  __syncthreads();

  int cur = 0;
  for (int s = 0; s < nsteps; ++s, cur ^= 1) {
    const int nxt = cur ^ 1;
    const bool more = (s + 1 < nsteps);
    short8v va, vb;
    if (more) {  // issue next step's loads before compute (latency hides)
      const int k0n = (s + 1) * 64;
      GL16(kptr + (size_t)(k0n + kr0) * DHEAD + kj0, sK[nxt] + t * 8);
      GL16(kptr + (size_t)(k0n + kr1) * DHEAD + kj1, sK[nxt] + (t + 256) * 8);
      va = *(const short8v*)(vtptr + (size_t)vr0 * SEQ + k0n + vo0);
      vb = *(const short8v*)(vtptr + (size_t)vr1 * SEQ + k0n + vo1);
    }
    {
      const int k0 = s * 64;
      const unsigned short* sKc = sK[cur];
      const unsigned short* sVc = sV[cur];
      // K frags: n4 = key group (0..3); row = n4*16+l15 (swizzled read)
      short8v kf[4][2];
#pragma unroll
      for (int n4 = 0; n4 < 4; n4++) {
        const int row = n4 * 16 + l15;
#pragma unroll
        for (int kk = 0; kk < 2; kk++)
          kf[n4][kk] = *(const short8v*)(sKc + row * 64 + (((kk * 4 + g) ^ (row & 7)) * 8));
      }
      // QK^T swapped: s4[n4] = D[key][q], key = k0+n4*16+4g+r, q = qrow = l15
      f32x4 s4[4];
#pragma unroll
      for (int n4 = 0; n4 < 4; n4++) s4[n4] = (f32x4){0.f, 0.f, 0.f, 0.f};
#pragma unroll
      for (int n4 = 0; n4 < 4; n4++)
#pragma unroll
        for (int kk = 0; kk < 2; kk++)
          s4[n4] = __builtin_amdgcn_mfma_f32_16x16x32_bf16(kf[n4][kk], qf[kk],
                                                           s4[n4], 0, 0, 0);
      if (s == nsteps - 1) {  // diagonal step: causal mask
#pragma unroll
        for (int n4 = 0; n4 < 4; n4++)
#pragma unroll
          for (int r = 0; r < 4; r++)
            if (k0 + n4 * 16 + 4 * g + r > qrow) s4[n4][r] = -__builtin_inff();
      }
      float mx = s4[0][0];
#pragma unroll
      for (int n4 = 0; n4 < 4; n4++)
#pragma unroll
        for (int r = 0; r < 4; r++)
          if (n4 || r) mx = fmaxf(mx, s4[n4][r]);
      if (!__all(mx <= rm)) {  // row max grew: reduce + rescale (rare)
        mx = fmaxf(mx, __shfl_xor(mx, 16));
        mx = fmaxf(mx, __shfl_xor(mx, 32));
        const float nm = fmaxf(rm, mx);
        const float al = exp2_hw(rm - nm);
        rm = nm;
#pragma unroll
        for (int r = 0; r < 4; r++) acc_l[r] *= al;
#pragma unroll
        for (int df = 0; df < 4; df++)
#pragma unroll
          for (int r = 0; r < 4; r++) acc_o[df][r] *= al;
      }
#pragma unroll
      for (int n4 = 0; n4 < 4; n4++)
#pragma unroll
        for (int r = 0; r < 4; r++) s4[n4][r] = exp2_hw(s4[n4][r] - rm);
      unsigned int pw[8];
#pragma unroll
      for (int n4 = 0; n4 < 4; n4++) {
        asm("v_cvt_pk_bf16_f32 %0, %1, %2"
            : "=v"(pw[n4 * 2]) : "v"(s4[n4][0]), "v"(s4[n4][1]));
        asm("v_cvt_pk_bf16_f32 %0, %1, %2"
            : "=v"(pw[n4 * 2 + 1]) : "v"(s4[n4][2]), "v"(s4[n4][3]));
      }
      union { short8v v; unsigned int wd[4]; } paA, paB;
      paA.wd[0] = pw[0]; paA.wd[1] = pw[1]; paA.wd[2] = pw[2]; paA.wd[3] = pw[3];
      paB.wd[0] = pw[4]; paB.wd[1] = pw[5]; paB.wd[2] = pw[6]; paB.wd[3] = pw[7];
      // denominator: all-ones A fragment -> every D row = sum_k P[k][q]
      acc_l = __builtin_amdgcn_mfma_f32_16x16x32_bf16(ones.v, paA.v, acc_l, 0, 0, 0);
      acc_l = __builtin_amdgcn_mfma_f32_16x16x32_bf16(ones.v, paB.v, acc_l, 0, 0, 0);
      // V frags + PV (vf read after softmax to cap register pressure)
#pragma unroll
      for (int df = 0; df < 4; df++) {
        const unsigned short* pv0 = sVc + (df * 16 + l15) * 72 + 4 * g;
        const short8v vfa = load_frag(pv0, pv0 + 16);
        acc_o[df] = __builtin_amdgcn_mfma_f32_16x16x32_bf16(vfa, paA.v, acc_o[df], 0, 0, 0);
        const unsigned short* pv1 = pv0 + 32;
        const short8v vfb = load_frag(pv1, pv1 + 16);
        acc_o[df] = __builtin_amdgcn_mfma_f32_16x16x32_bf16(vfb, paB.v, acc_o[df], 0, 0, 0);
      }
    }
    if (more) {
      *(short8v*)(sV[nxt] + vr0 * 72 + vo0) = va;
      *(short8v*)(sV[nxt] + vr1 * 72 + vo1) = vb;
    }
    __syncthreads();
  }

  // epilogue: denominator complete per-lane (MFMA already reduced over keys)
  const int bb = bh >> 4, hh = bh & 15;
  const float inv = 1.0f / acc_l[0];
#pragma unroll
  for (int df = 0; df < 4; df++) {
    union { short4v v; unsigned short u[4]; } pk4;
#pragma unroll
    for (int r = 0; r < 4; r++) pk4.u[r] = f2bf(acc_o[df][r] * inv);
    *(short4v*)(ob + ((size_t)bb * SEQ + qrow) * DINNER + hh * DHEAD + df * 16 + 4 * g) =
        pk4.v;
  }
}

extern "C" void kernel_launch(void* const* d_in, const int* in_sizes, int n_in,
                              void* d_out, int out_size, void* d_ws, size_t ws_size,
                              hipStream_t stream) {
  (void)in_sizes; (void)n_in; (void)out_size; (void)ws_size;
  const float* x = (const float*)d_in[0];
  const float* gamma = (const float*)d_in[1];
  const float* w_qkv = (const float*)d_in[2];
  const float* w_out = (const float*)d_in[3];
  float* out = (float*)d_out;
  char* ws = (char*)d_ws;
  unsigned short* wqkvT = (unsigned short*)(ws);                // 6291456 B
  unsigned short* woutT = (unsigned short*)(ws + 6291456);      // 2097152 B
  unsigned short* normed = (unsigned short*)(ws + 8388608);     // 8388608 B
  unsigned short* qbuf = (unsigned short*)(ws + 16777216);      // 8388608 B
  unsigned short* kbuf = (unsigned short*)(ws + 25165824);      // 8388608 B
  unsigned short* vtbuf = (unsigned short*)(ws + 33554432);     // 8388608 B (transposed V)
  unsigned short* aout = (unsigned short*)(ws + 41943040);      // 8388608 B

  hipLaunchKernelGGL(transpose_cast_kernel, dim3((DMODEL / 32) * (NQKV / 32)), dim3(256), 0,
                     stream, w_qkv, wqkvT, DMODEL, NQKV);
  hipLaunchKernelGGL(transpose_cast_kernel, dim3((DINNER / 32) * (DMODEL / 32)), dim3(256), 0,
                     stream, w_out, woutT, DINNER, DMODEL);
  hipLaunchKernelGGL(rmsnorm_kernel, dim3(BATCH * SEQ), dim3(256), 0, stream, x, gamma, normed);
  hipLaunchKernelGGL(qkv_gemm_kernel, dim3((BATCH * SEQ / BM) * (NQKV / BN)), dim3(256), 0,
                     stream, normed, wqkvT, qbuf, kbuf, vtbuf);
  hipLaunchKernelGGL(attn_kernel, dim3(BATCH * NHEAD * 32), dim3(256), 0, stream,
                     qbuf, kbuf, vtbuf, aout);
  hipLaunchKernelGGL(out_gemm_kernel, dim3((BATCH * SEQ / BM) * (DMODEL / BN)), dim3(256), 0,
                     stream, aout, woutT, out);
}

// Round 13
// 110.567 us; speedup vs baseline: 1.0779x; 1.0503x over previous
//
#include <hip/hip_runtime.h>
#include <hip/hip_bf16.h>

#define BATCH 2
#define SEQ 2048
#define DMODEL 1024
#define NHEAD 16
#define DHEAD 64
#define NQKV 3072
#define DINNER 1024

typedef __attribute__((ext_vector_type(4))) short short4v;
typedef __attribute__((ext_vector_type(8))) short short8v;
typedef __attribute__((ext_vector_type(4))) float f32x4;

__device__ __forceinline__ unsigned short f2bf(float f) {
  union { float f; unsigned int u; } c; c.f = f;
  unsigned int u = c.u;
  u += 0x7fffu + ((u >> 16) & 1u);
  return (unsigned short)(u >> 16);
}

__device__ __forceinline__ float exp2_hw(float x) {  // v_exp_f32: D = 2^S0
  float r;
  asm("v_exp_f32 %0, %1" : "=v"(r) : "v"(x));
  return r;
}

#define GL16(gp, lp)                                             \
  __builtin_amdgcn_global_load_lds(                              \
      (__attribute__((address_space(1))) void*)(gp),             \
      (__attribute__((address_space(3))) void*)(lp), 16, 0, 0)

// ---------------- transpose + cast fp32 [K][N] -> bf16 [N][K] ----------------
__global__ __launch_bounds__(256) void transpose_cast_kernel(const float* __restrict__ in,
                                                             unsigned short* __restrict__ out,
                                                             int K, int N) {
  __shared__ float tile[32][33];
  const int tiles_n = N >> 5;
  const int tn = blockIdx.x % tiles_n;
  const int tk = blockIdx.x / tiles_n;
  const int k0 = tk << 5, n0 = tn << 5;
  const int t = threadIdx.x;
#pragma unroll
  for (int p = 0; p < 4; p++) {
    const int e = p * 256 + t;
    const int r = e >> 5, c = e & 31;
    tile[r][c] = in[(size_t)(k0 + r) * N + n0 + c];
  }
  __syncthreads();
#pragma unroll
  for (int p = 0; p < 4; p++) {
    const int e = p * 256 + t;
    const int r = e >> 5, c = e & 31;
    out[(size_t)(n0 + r) * K + k0 + c] = f2bf(tile[c][r]);
  }
}

// ---------------- RMSNorm (F.normalize * sqrt(dim) * gamma) -> bf16 ----------
__global__ __launch_bounds__(256) void rmsnorm_kernel(const float* __restrict__ x,
                                                      const float* __restrict__ gamma,
                                                      unsigned short* __restrict__ out) {
  const int row = blockIdx.x;
  const int t = threadIdx.x;
  const float* xr = x + (size_t)row * DMODEL;
  float4 v = ((const float4*)xr)[t];
  float ss = v.x * v.x + v.y * v.y + v.z * v.z + v.w * v.w;
#pragma unroll
  for (int off = 1; off < 64; off <<= 1) ss += __shfl_xor(ss, off);
  __shared__ float wss[4];
  if ((t & 63) == 0) wss[t >> 6] = ss;
  __syncthreads();
  const float tot = wss[0] + wss[1] + wss[2] + wss[3];
  float l2 = sqrtf(tot);
  l2 = fmaxf(l2, 1e-12f);
  const float s = 32.0f / l2;  // sqrt(1024)/l2
  const float4 gm = ((const float4*)gamma)[t];
  unsigned short o[4];
  o[0] = f2bf(v.x * s * gm.x);
  o[1] = f2bf(v.y * s * gm.y);
  o[2] = f2bf(v.z * s * gm.z);
  o[3] = f2bf(v.w * s * gm.w);
  unsigned short* op = out + (size_t)row * DMODEL + t * 4;
  *(short4v*)op = *(short4v*)o;
}

// ---------------- shared GEMM core: double-buffered global_load_lds staging --
#define BM 128
#define BN 128
#define BKT 32
#define TILE_E (BM * BKT)

__device__ void gemm_core(const unsigned short* __restrict__ A,
                          const unsigned short* __restrict__ Bt, int K, int rowBase,
                          int colBase, unsigned short* sA, unsigned short* sB,
                          f32x4 acc[4][4]) {
  const int t = threadIdx.x;
  const int lane = t & 63, wave = t >> 6;
  const int l15 = lane & 15, g = lane >> 4;
  const int wr = (wave >> 1) * 64, wc = (wave & 1) * 64;
#pragma unroll
  for (int m = 0; m < 4; m++)
#pragma unroll
    for (int n = 0; n < 4; n++) acc[m][n] = (f32x4){0.f, 0.f, 0.f, 0.f};
  const int r0 = t >> 2, o0 = (t & 3) * 8;
  const unsigned short* Ag0 = A + (size_t)(rowBase + r0) * K + o0;
  const unsigned short* Ag1 = A + (size_t)(rowBase + r0 + 64) * K + o0;
  const unsigned short* Bg0 = Bt + (size_t)(colBase + r0) * K + o0;
  const unsigned short* Bg1 = Bt + (size_t)(colBase + r0 + 64) * K + o0;
  // prologue: tile 0 -> half 0
  GL16(Ag0, sA + t * 8);
  GL16(Ag1, sA + (t + 256) * 8);
  GL16(Bg0, sB + t * 8);
  GL16(Bg1, sB + (t + 256) * 8);
  __syncthreads();  // drains vmcnt -> tile 0 resident
  int cur = 0;
  for (int k0 = 0; k0 < K; k0 += BKT, cur ^= 1) {
    if (k0 + BKT < K) {  // prefetch next tile into the other half
      const int nxto = (cur ^ 1) * TILE_E;
      GL16(Ag0 + k0 + BKT, sA + nxto + t * 8);
      GL16(Ag1 + k0 + BKT, sA + nxto + (t + 256) * 8);
      GL16(Bg0 + k0 + BKT, sB + nxto + t * 8);
      GL16(Bg1 + k0 + BKT, sB + nxto + (t + 256) * 8);
    }
    const unsigned short* sAc = sA + cur * TILE_E;
    const unsigned short* sBc = sB + cur * TILE_E;
    short8v af[4], bf[4];
#pragma unroll
    for (int m = 0; m < 4; m++)
      af[m] = *(const short8v*)(sAc + (wr + m * 16 + l15) * BKT + 8 * g);
#pragma unroll
    for (int n = 0; n < 4; n++)
      bf[n] = *(const short8v*)(sBc + (wc + n * 16 + l15) * BKT + 8 * g);
#pragma unroll
    for (int m = 0; m < 4; m++)
#pragma unroll
      for (int n = 0; n < 4; n++)
        acc[m][n] = __builtin_amdgcn_mfma_f32_16x16x32_bf16(af[m], bf[n], acc[m][n], 0, 0, 0);
    __syncthreads();  // waves done with cur + prefetch complete
  }
}

// ---------------- QKV GEMM + scatter epilogue (V stored transposed) ----------
// q pre-scaled by d^-0.5 * log2(e) so attention softmax runs in exp2 domain.
// V^T columns are PERMUTED within each 32-key group (pos = [g][a][j] for key
// 16a+4g+j) so attn's PV B-fragment is one contiguous b128 per (df,ks).
__global__ __launch_bounds__(256) void qkv_gemm_kernel(const unsigned short* __restrict__ A,
                                                       const unsigned short* __restrict__ Bt,
                                                       unsigned short* __restrict__ qb,
                                                       unsigned short* __restrict__ kb,
                                                       unsigned short* __restrict__ vtb) {
  __shared__ __align__(16) unsigned short sA[2 * TILE_E];
  __shared__ __align__(16) unsigned short sB[2 * TILE_E];
  const int nbn = NQKV / BN;  // 24
  const int bm = blockIdx.x / nbn, bn = blockIdx.x % nbn;
  f32x4 acc[4][4];
  gemm_core(A, Bt, DMODEL, bm * BM, bn * BN, sA, sB, acc);
  const int t = threadIdx.x, lane = t & 63, wave = t >> 6;
  const int l15 = lane & 15, g = lane >> 4;
  const int wr = (wave >> 1) * 64, wc = (wave & 1) * 64;
#pragma unroll
  for (int m = 0; m < 4; m++)
#pragma unroll
    for (int n = 0; n < 4; n++) {
      const int col = bn * BN + wc + n * 16 + l15;
      const int part = col >> 10;
      const int h = (col >> 6) & 15;
      const int d = col & 63;
      const int row0 = bm * BM + wr + m * 16 + 4 * g;
      const int bb = row0 >> 11, i0 = row0 & 2047;
      if (part == 2) {
        // permuted V^T: key i -> pos (i&~31)|((i>>2)&3)<<3|((i>>4)&1)<<2|(i&3)
        // i0 is 4-aligned so the 4 consecutive keys stay one short4v store
        const int ip = (i0 & ~31) | (((i0 >> 2) & 3) << 3) | (((i0 >> 4) & 1) << 2);
        union { short4v v; unsigned short u[4]; } pk;
#pragma unroll
        for (int r = 0; r < 4; r++) pk.u[r] = f2bf(acc[m][n][r]);
        *(short4v*)(vtb + ((size_t)(bb * NHEAD + h) * DHEAD + d) * SEQ + ip) = pk.v;
      } else {
#pragma unroll
        for (int r = 0; r < 4; r++) {
          const size_t idx = (((size_t)(bb * NHEAD + h)) * SEQ + i0 + r) * DHEAD + d;
          const float v = acc[m][n][r];
          if (part == 0) qb[idx] = f2bf(v * 0.18033688f);  // 0.125 * log2(e)
          else kb[idx] = f2bf(v);
        }
      }
    }
}

// ---------------- output GEMM: d_out = attn_out @ w_out ----------------------
__global__ __launch_bounds__(256) void out_gemm_kernel(const unsigned short* __restrict__ A,
                                                       const unsigned short* __restrict__ Bt,
                                                       float* __restrict__ C) {
  __shared__ __align__(16) unsigned short sA[2 * TILE_E];
  __shared__ __align__(16) unsigned short sB[2 * TILE_E];
  const int nbn = DMODEL / BN;  // 8
  const int bm = blockIdx.x / nbn, bn = blockIdx.x % nbn;
  f32x4 acc[4][4];
  gemm_core(A, Bt, DINNER, bm * BM, bn * BN, sA, sB, acc);
  const int t = threadIdx.x, lane = t & 63, wave = t >> 6;
  const int l15 = lane & 15, g = lane >> 4;
  const int wr = (wave >> 1) * 64, wc = (wave & 1) * 64;
#pragma unroll
  for (int m = 0; m < 4; m++)
#pragma unroll
    for (int n = 0; n < 4; n++) {
      const int col = bn * BN + wc + n * 16 + l15;
#pragma unroll
      for (int r = 0; r < 4; r++) {
        const int row = bm * BM + wr + m * 16 + 4 * g + r;
        C[(size_t)row * DMODEL + col] = acc[m][n][r];
      }
    }
}

// ---------------- causal flash attention: 64-row blocks, 4 blocks/CU ---------
// R9 structure: block = 64 q-rows (4 waves x 16), grid 1024 -> 4 INDEPENDENT
// blocks/CU overlap barrier drains; constant-sum qblk map equalizes
// co-resident step totals. K via global_load_lds + both-sides XOR swizzle.
// V^T (column-permuted by the producer) reg-staged into padded [64][72];
// PV B-frags are single b128 reads at bank-uniform addresses (the former
// 16x ds_read_b64 split pattern was the 4.3M-cycle bank-conflict source).
// exp2-domain softmax + MFMA ones-fragment denominator.
__global__ __launch_bounds__(256, 4) void attn_kernel(const unsigned short* __restrict__ qb,
                                                      const unsigned short* __restrict__ kb,
                                                      const unsigned short* __restrict__ vtb,
                                                      unsigned short* __restrict__ ob) {
  __shared__ __align__(16) unsigned short sK[2][64 * 64];  // 8KB each, swizzled
  __shared__ __align__(16) unsigned short sV[2][64 * 72];  // padded rows (144B)
  const int t = threadIdx.x, lane = t & 63, wave = t >> 6;
  const int l15 = lane & 15, g = lane >> 4;
  const int bh = blockIdx.x & 31;        // low bits -> same-bh blocks same XCD
  const int qord = blockIdx.x >> 5;      // 0..31
  // constant-sum map: co-resident quadruple {q, q+8, q+16, q+24} sums to 62
  const int qblk = (qord < 8) ? 31 - qord
                 : (qord < 16) ? qord - 8
                 : (qord < 24) ? 39 - qord
                 : qord - 16;
  const int qrow = qblk * 64 + wave * 16 + l15;
  const unsigned short* qptr = qb + (size_t)bh * SEQ * DHEAD;
  const unsigned short* kptr = kb + (size_t)bh * SEQ * DHEAD;
  const unsigned short* vtptr = vtb + (size_t)bh * DHEAD * SEQ;

  // staging geometry (256 threads, 2 x 16B chunks each for K and V)
  const int kr0 = t >> 3, kj0 = ((t & 7) ^ (kr0 & 7)) * 8;
  const int kr1 = (t + 256) >> 3, kj1 = ((t & 7) ^ (kr1 & 7)) * 8;
  const int vr0 = t >> 3, vo0 = (t & 7) * 8;
  const int vr1 = (t + 256) >> 3, vo1 = (t & 7) * 8;

  // Q fragments (B operand): l15 = q, elems = d (contiguous 8)
  short8v qf[2];
#pragma unroll
  for (int kk = 0; kk < 2; kk++)
    qf[kk] = *(const short8v*)(qptr + (size_t)qrow * DHEAD + kk * 32 + 8 * g);

  // all-ones bf16 fragment for the denominator MFMA
  union { short8v v; unsigned short u[8]; } ones;
#pragma unroll
  for (int j = 0; j < 8; j++) ones.u[j] = 0x3F80;

  float rm = -__builtin_inff();
  f32x4 acc_l = (f32x4){0.f, 0.f, 0.f, 0.f};  // denominator (rows identical)
  f32x4 acc_o[4];  // [df]: col = q = l15, row(4g+r) = d = df*16+4g+r
#pragma unroll
  for (int df = 0; df < 4; df++) acc_o[df] = (f32x4){0.f, 0.f, 0.f, 0.f};

  const int nsteps = qblk + 1;  // 64-key steps

  // prologue: stage step 0 into buf 0
  GL16(kptr + (size_t)kr0 * DHEAD + kj0, sK[0] + t * 8);
  GL16(kptr + (size_t)kr1 * DHEAD + kj1, sK[0] + (t + 256) * 8);
  {
    short8v va = *(const short8v*)(vtptr + (size_t)vr0 * SEQ + vo0);
    short8v vb = *(const short8v*)(vtptr + (size_t)vr1 * SEQ + vo1);
    *(short8v*)(sV[0] + vr0 * 72 + vo0) = va;
    *(short8v*)(sV[0] + vr1 * 72 + vo1) = vb;
  }
  __syncthreads();

  int cur = 0;
  for (int s = 0; s < nsteps; ++s, cur ^= 1) {
    const int nxt = cur ^ 1;
    const bool more = (s + 1 < nsteps);
    short8v va, vb;
    if (more) {  // issue next step's loads before compute (latency hides)
      const int k0n = (s + 1) * 64;
      GL16(kptr + (size_t)(k0n + kr0) * DHEAD + kj0, sK[nxt] + t * 8);
      GL16(kptr + (size_t)(k0n + kr1) * DHEAD + kj1, sK[nxt] + (t + 256) * 8);
      va = *(const short8v*)(vtptr + (size_t)vr0 * SEQ + k0n + vo0);
      vb = *(const short8v*)(vtptr + (size_t)vr1 * SEQ + k0n + vo1);
    }
    {
      const int k0 = s * 64;
      const unsigned short* sKc = sK[cur];
      const unsigned short* sVc = sV[cur];
      // K frags: n4 = key group (0..3); row = n4*16+l15 (swizzled read)
      short8v kf[4][2];
#pragma unroll
      for (int n4 = 0; n4 < 4; n4++) {
        const int row = n4 * 16 + l15;
#pragma unroll
        for (int kk = 0; kk < 2; kk++)
          kf[n4][kk] = *(const short8v*)(sKc + row * 64 + (((kk * 4 + g) ^ (row & 7)) * 8));
      }
      // QK^T swapped: s4[n4] = D[key][q], key = k0+n4*16+4g+r, q = qrow = l15
      f32x4 s4[4];
#pragma unroll
      for (int n4 = 0; n4 < 4; n4++) s4[n4] = (f32x4){0.f, 0.f, 0.f, 0.f};
#pragma unroll
      for (int n4 = 0; n4 < 4; n4++)
#pragma unroll
        for (int kk = 0; kk < 2; kk++)
          s4[n4] = __builtin_amdgcn_mfma_f32_16x16x32_bf16(kf[n4][kk], qf[kk],
                                                           s4[n4], 0, 0, 0);
      if (s == nsteps - 1) {  // diagonal step: causal mask
#pragma unroll
        for (int n4 = 0; n4 < 4; n4++)
#pragma unroll
          for (int r = 0; r < 4; r++)
            if (k0 + n4 * 16 + 4 * g + r > qrow) s4[n4][r] = -__builtin_inff();
      }
      float mx = s4[0][0];
#pragma unroll
      for (int n4 = 0; n4 < 4; n4++)
#pragma unroll
        for (int r = 0; r < 4; r++)
          if (n4 || r) mx = fmaxf(mx, s4[n4][r]);
      if (!__all(mx <= rm)) {  // row max grew: reduce + rescale (rare)
        mx = fmaxf(mx, __shfl_xor(mx, 16));
        mx = fmaxf(mx, __shfl_xor(mx, 32));
        const float nm = fmaxf(rm, mx);
        const float al = exp2_hw(rm - nm);
        rm = nm;
#pragma unroll
        for (int r = 0; r < 4; r++) acc_l[r] *= al;
#pragma unroll
        for (int df = 0; df < 4; df++)
#pragma unroll
          for (int r = 0; r < 4; r++) acc_o[df][r] *= al;
      }
#pragma unroll
      for (int n4 = 0; n4 < 4; n4++)
#pragma unroll
        for (int r = 0; r < 4; r++) s4[n4][r] = exp2_hw(s4[n4][r] - rm);
      unsigned int pw[8];
#pragma unroll
      for (int n4 = 0; n4 < 4; n4++) {
        asm("v_cvt_pk_bf16_f32 %0, %1, %2"
            : "=v"(pw[n4 * 2]) : "v"(s4[n4][0]), "v"(s4[n4][1]));
        asm("v_cvt_pk_bf16_f32 %0, %1, %2"
            : "=v"(pw[n4 * 2 + 1]) : "v"(s4[n4][2]), "v"(s4[n4][3]));
      }
      union { short8v v; unsigned int wd[4]; } paA, paB;
      paA.wd[0] = pw[0]; paA.wd[1] = pw[1]; paA.wd[2] = pw[2]; paA.wd[3] = pw[3];
      paB.wd[0] = pw[4]; paB.wd[1] = pw[5]; paB.wd[2] = pw[6]; paB.wd[3] = pw[7];
      // denominator: all-ones A fragment -> every D row = sum_k P[k][q]
      acc_l = __builtin_amdgcn_mfma_f32_16x16x32_bf16(ones.v, paA.v, acc_l, 0, 0, 0);
      acc_l = __builtin_amdgcn_mfma_f32_16x16x32_bf16(ones.v, paB.v, acc_l, 0, 0, 0);
      // V frags: permuted layout -> one b128 per (df, ks); bank-uniform
#pragma unroll
      for (int df = 0; df < 4; df++) {
        const unsigned short* pv = sVc + (df * 16 + l15) * 72 + 8 * g;
        const short8v vfa = *(const short8v*)(pv);
        acc_o[df] = __builtin_amdgcn_mfma_f32_16x16x32_bf16(vfa, paA.v, acc_o[df], 0, 0, 0);
        const short8v vfb = *(const short8v*)(pv + 32);
        acc_o[df] = __builtin_amdgcn_mfma_f32_16x16x32_bf16(vfb, paB.v, acc_o[df], 0, 0, 0);
      }
    }
    if (more) {
      *(short8v*)(sV[nxt] + vr0 * 72 + vo0) = va;
      *(short8v*)(sV[nxt] + vr1 * 72 + vo1) = vb;
    }
    __syncthreads();
  }

  // epilogue: denominator complete per-lane (MFMA already reduced over keys)
  const int bb = bh >> 4, hh = bh & 15;
  const float inv = 1.0f / acc_l[0];
#pragma unroll
  for (int df = 0; df < 4; df++) {
    union { short4v v; unsigned short u[4]; } pk4;
#pragma unroll
    for (int r = 0; r < 4; r++) pk4.u[r] = f2bf(acc_o[df][r] * inv);
    *(short4v*)(ob + ((size_t)bb * SEQ + qrow) * DINNER + hh * DHEAD + df * 16 + 4 * g) =
        pk4.v;
  }
}

extern "C" void kernel_launch(void* const* d_in, const int* in_sizes, int n_in,
                              void* d_out, int out_size, void* d_ws, size_t ws_size,
                              hipStream_t stream) {
  (void)in_sizes; (void)n_in; (void)out_size; (void)ws_size;
  const float* x = (const float*)d_in[0];
  const float* gamma = (const float*)d_in[1];
  const float* w_qkv = (const float*)d_in[2];
  const float* w_out = (const float*)d_in[3];
  float* out = (float*)d_out;
  char* ws = (char*)d_ws;
  unsigned short* wqkvT = (unsigned short*)(ws);                // 6291456 B
  unsigned short* woutT = (unsigned short*)(ws + 6291456);      // 2097152 B
  unsigned short* normed = (unsigned short*)(ws + 8388608);     // 8388608 B
  unsigned short* qbuf = (unsigned short*)(ws + 16777216);      // 8388608 B
  unsigned short* kbuf = (unsigned short*)(ws + 25165824);      // 8388608 B
  unsigned short* vtbuf = (unsigned short*)(ws + 33554432);     // 8388608 B (permuted V^T)
  unsigned short* aout = (unsigned short*)(ws + 41943040);      // 8388608 B

  hipLaunchKernelGGL(transpose_cast_kernel, dim3((DMODEL / 32) * (NQKV / 32)), dim3(256), 0,
                     stream, w_qkv, wqkvT, DMODEL, NQKV);
  hipLaunchKernelGGL(transpose_cast_kernel, dim3((DINNER / 32) * (DMODEL / 32)), dim3(256), 0,
                     stream, w_out, woutT, DINNER, DMODEL);
  hipLaunchKernelGGL(rmsnorm_kernel, dim3(BATCH * SEQ), dim3(256), 0, stream, x, gamma, normed);
  hipLaunchKernelGGL(qkv_gemm_kernel, dim3((BATCH * SEQ / BM) * (NQKV / BN)), dim3(256), 0,
                     stream, normed, wqkvT, qbuf, kbuf, vtbuf);
  hipLaunchKernelGGL(attn_kernel, dim3(BATCH * NHEAD * 32), dim3(256), 0, stream,
                     qbuf, kbuf, vtbuf, aout);
  hipLaunchKernelGGL(out_gemm_kernel, dim3((BATCH * SEQ / BM) * (DMODEL / BN)), dim3(256), 0,
                     stream, aout, woutT, out);
}